// Round 11
// baseline (540.391 us; speedup 1.0000x reference)
//
#include <hip/hip_runtime.h>

typedef __bf16 bf16x8_t __attribute__((ext_vector_type(8)));
typedef float f32x4_t __attribute__((ext_vector_type(4)));

#define LAT_LD 1664
#define QK_DIM 576
#define V_DIM 512
#define NHEAD 16
#define TSEQ 2048
#define QLD 9216
#define YLD 8192
#define KLD 576
#define SCALE 0.044194173824159216f

__device__ __forceinline__ unsigned short f2bf(float f) {
  union { float f; unsigned int u; } v; v.f = f;
  unsigned int r = v.u + 0x7FFFu + ((v.u >> 16) & 1u);
  return (unsigned short)(r >> 16);
}

// async global->LDS 16B (m97 pattern). LDS dest must be wave-uniform base + lane*16.
__device__ __forceinline__ void load_lds16(const unsigned short* g, unsigned short* l) {
  __builtin_amdgcn_global_load_lds((const __attribute__((address_space(1))) void*)g,
                                   (__attribute__((address_space(3))) void*)l, 16, 0, 0);
}

// ---------------- fused prep: x->bf16, 3x transpose-convert, lsum zero ----------------
__device__ __forceinline__ void conv_t_body(const float* __restrict__ src, int R, int Csrc,
                                            unsigned short* __restrict__ dst,
                                            int bx, int by, int tid,
                                            unsigned short (*T)[72]) {
  const int r0 = bx * 64, c0 = by * 64;
  const bool live = (c0 < Csrc);
#pragma unroll
  for (int it = 0; it < 4; ++it) {
    int idx = it * 256 + tid;
    int r = idx >> 4, c4 = (idx & 15) * 4;   // row-contiguous: coalesced fp32 reads
    float4 v = {0.f, 0.f, 0.f, 0.f};
    if (live) v = *(const float4*)&src[(size_t)(r0 + r) * Csrc + c0 + c4];
    T[c4 + 0][r] = f2bf(v.x);
    T[c4 + 1][r] = f2bf(v.y);
    T[c4 + 2][r] = f2bf(v.z);
    T[c4 + 3][r] = f2bf(v.w);
  }
  __syncthreads();
#pragma unroll
  for (int it = 0; it < 2; ++it) {
    int idx = it * 256 + tid;
    int cc = idx >> 3, r8 = (idx & 7) * 8;
    uint4 v = *(const uint4*)&T[cc][r8];
    *(uint4*)&dst[(size_t)(c0 + cc) * R + r0 + r8] = v;
  }
}

// jobs: [0,4096) conv x; [4096,4928) wqkvT; [4928,7232) wqdecT; [7232,11328) woutT;
//       [11328,11360) zero lsum
__global__ __launch_bounds__(256) void prep_all(
    const float* __restrict__ x, unsigned short* __restrict__ xb,
    const float* __restrict__ wqkv, unsigned short* __restrict__ wqkvT,
    const float* __restrict__ wqdec, unsigned short* __restrict__ wqdecT,
    const float* __restrict__ wout, unsigned short* __restrict__ woutT,
    float* __restrict__ lsum) {
  __shared__ unsigned short T[64][72];
  const int blk = blockIdx.x, tid = threadIdx.x;
  if (blk < 4096) {
    int i = (blk * 256 + tid) * 4;
    float4 v = *(const float4*)&x[i];
    ushort4 o;
    o.x = f2bf(v.x); o.y = f2bf(v.y); o.z = f2bf(v.z); o.w = f2bf(v.w);
    *(ushort4*)&xb[i] = o;
  } else if (blk < 4928) {
    int l = blk - 4096;
    conv_t_body(wqkv, 2048, 1600, wqkvT, l & 31, l >> 5, tid, T);
  } else if (blk < 7232) {
    int l = blk - 4928;
    conv_t_body(wqdec, 1024, 9216, wqdecT, l & 15, l >> 4, tid, T);
  } else if (blk < 11328) {
    int l = blk - 7232;
    conv_t_body(wout, 8192, 2048, woutT, l & 127, l >> 7, tid, T);
  } else {
    int i = ((blk - 11328) * 256 + tid) * 4;
    *(float4*)&lsum[i] = (float4){0.f, 0.f, 0.f, 0.f};
  }
}

// ---------------- fused post-gemm1: reduce split-K partials + RoPE-K + V-transpose ----------------
__global__ __launch_bounds__(256) void postlat(
    const float* __restrict__ P1,
    unsigned short* __restrict__ lat,
    unsigned short* __restrict__ kbuf,
    unsigned short* __restrict__ vtg,
    const float* __restrict__ cosb, const float* __restrict__ sinb) {
  __shared__ unsigned short T[64][72];
  const int tid = threadIdx.x;
  const int bx = blockIdx.x, by = blockIdx.y;
  const int r0 = bx * 64, c0 = by * 64;
  const size_t n = (size_t)2048 * 1664;

#pragma unroll
  for (int it = 0; it < 4; ++it) {
    int idx = it * 256 + tid;
    int r = idx >> 4, c4 = (idx & 15) * 4;
    size_t off = (size_t)(r0 + r) * 1664 + c0 + c4;
    float4 a = *(const float4*)&P1[off];
    float4 b = *(const float4*)&P1[n + off];
    ushort4 o;
    o.x = f2bf(a.x + b.x); o.y = f2bf(a.y + b.y);
    o.z = f2bf(a.z + b.z); o.w = f2bf(a.w + b.w);
    if (by < 8) {
      *(ushort4*)&kbuf[(size_t)(r0 + r) * KLD + c0 + c4] = o;
      T[c4 + 0][r] = o.x; T[c4 + 1][r] = o.y; T[c4 + 2][r] = o.z; T[c4 + 3][r] = o.w;
    } else if (by == 8) {
      T[r][c4 + 0] = o.x; T[r][c4 + 1] = o.y; T[r][c4 + 2] = o.z; T[r][c4 + 3] = o.w;
    } else {
      *(ushort4*)&lat[(size_t)(r0 + r) * LAT_LD + c0 + c4] = o;
    }
  }
  if (by > 8) return;
  __syncthreads();
  if (by < 8) {
#pragma unroll
    for (int it = 0; it < 2; ++it) {
      int idx = it * 256 + tid;
      int cc = idx >> 3, r8 = (idx & 7) * 8;
      uint4 v = *(const uint4*)&T[cc][r8];
      *(uint4*)&vtg[(size_t)(c0 + cc) * TSEQ + r0 + r8] = v;
    }
  } else {
#pragma unroll
    for (int it = 0; it < 8; ++it) {
      int idx = it * 256 + tid;
      int r = idx >> 5, d = idx & 31;
      int t = r0 + r;
      union { unsigned int u; float f; } a, b;
      a.u = ((unsigned int)T[r][d]) << 16;
      b.u = ((unsigned int)T[r][d + 32]) << 16;
      float c0f = cosb[t * 64 + d], s0f = sinb[t * 64 + d];
      float c1f = cosb[t * 64 + d + 32], s1f = sinb[t * 64 + d + 32];
      kbuf[(size_t)t * KLD + 512 + d] = f2bf(a.f * c0f - b.f * s0f);
      kbuf[(size_t)t * KLD + 544 + d] = f2bf(b.f * c1f + a.f * s1f);
    }
  }
}

// ---------------- m97-style GEMM core, BK=64 (gemm1 / qdec / pv) ----------------
#define GEMM_PROLOGUE()                                                     \
  __shared__ __align__(16) unsigned short As[8192];                         \
  __shared__ __align__(16) unsigned short Bs[8192];                         \
  const int tid = threadIdx.x;                                              \
  const int wave = tid >> 6, lane = tid & 63;                               \
  const int quad = lane >> 4, l16 = lane & 15;                              \
  const int wm = wave >> 1, wn = wave & 1;                                  \
  f32x4_t acc[4][4];                                                        \
  f32x4_t zero = {0.f, 0.f, 0.f, 0.f};                                      \
  _Pragma("unroll") for (int mi = 0; mi < 4; ++mi)                          \
    _Pragma("unroll") for (int ni = 0; ni < 4; ++ni) acc[mi][ni] = zero;

#define GEMM_KLOOP(Aptr, Alda, Bptr, Bldb, M0, N0, KLEN)                    \
  for (int k0 = 0; k0 < (KLEN); k0 += 64) {                                 \
    _Pragma("unroll") for (int p2 = 0; p2 < 2; ++p2) {                      \
      int ci = p2 * 256 + tid;                                              \
      int rr2 = ci >> 2, cc2 = (ci & 3) * 8;                                \
      const unsigned short* ga = &(Aptr)[(size_t)((M0) + rr2) * (Alda) + k0 + cc2]; \
      const unsigned short* gb = &(Bptr)[(size_t)((N0) + rr2) * (Bldb) + k0 + cc2]; \
      load_lds16(ga,      &As[ci * 8]);                                     \
      load_lds16(ga + 32, &As[4096 + ci * 8]);                              \
      load_lds16(gb,      &Bs[ci * 8]);                                     \
      load_lds16(gb + 32, &Bs[4096 + ci * 8]);                              \
    }                                                                       \
    __syncthreads();                                                        \
    _Pragma("unroll") for (int hf = 0; hf < 2; ++hf) {                      \
      bf16x8_t af[4], bfr[4];                                               \
      _Pragma("unroll") for (int mi = 0; mi < 4; ++mi)                      \
        af[mi] = *(const bf16x8_t*)&As[hf * 4096 + (wm * 64 + mi * 16 + l16) * 32 + quad * 8]; \
      _Pragma("unroll") for (int ni = 0; ni < 4; ++ni)                      \
        bfr[ni] = *(const bf16x8_t*)&Bs[hf * 4096 + (wn * 64 + ni * 16 + l16) * 32 + quad * 8]; \
      _Pragma("unroll") for (int mi = 0; mi < 4; ++mi)                      \
        _Pragma("unroll") for (int ni = 0; ni < 4; ++ni)                    \
          acc[mi][ni] = __builtin_amdgcn_mfma_f32_16x16x32_bf16(af[mi], bfr[ni], acc[mi][ni], 0, 0, 0); \
    }                                                                       \
    __syncthreads();                                                        \
  }

// ---------------- split-K GEMM (128^2, used for gemm1) ----------------
__global__ __launch_bounds__(256, 2) void gemm_splitk(
    const unsigned short* __restrict__ A, int lda,
    const unsigned short* __restrict__ Bt, int ldb,
    float* __restrict__ P, int ldc, int Ks) {
  const int m0 = blockIdx.y * 128, n0 = blockIdx.x * 128;
  const size_t koff = (size_t)blockIdx.z * Ks;
  const unsigned short* Ap = A + koff;
  const unsigned short* Bp = Bt + koff;
  float* C = P + (size_t)blockIdx.z * ((size_t)gridDim.y * 128) * ldc;
  GEMM_PROLOGUE();
  GEMM_KLOOP(Ap, lda, Bp, ldb, m0, n0, Ks);
#pragma unroll
  for (int mi = 0; mi < 4; ++mi)
#pragma unroll
    for (int ni = 0; ni < 4; ++ni)
#pragma unroll
      for (int r = 0; r < 4; ++r) {
        int row = m0 + wm * 64 + mi * 16 + quad * 4 + r;
        int col = n0 + wn * 64 + ni * 16 + l16;
        C[(size_t)row * ldc + col] = acc[mi][ni][r];
      }
}

// ---------------- gemm2 with fused RoPE-q epilogue (128^2 core, balanced grid) ------------
__global__ __launch_bounds__(256, 2) void gemm_qdec(
    const unsigned short* __restrict__ A,      // lat + 576 (c_q), lda LAT_LD
    const unsigned short* __restrict__ Bt,     // wqdecT [9216][1024]
    unsigned short* __restrict__ qbuf,
    const float* __restrict__ cosb, const float* __restrict__ sinb) {
  const int m0 = blockIdx.y * 128, n0 = blockIdx.x * 128;
  GEMM_PROLOGUE();
  GEMM_KLOOP(A, LAT_LD, Bt, 1024, m0, n0, 1024);

  const int cb = n0 + wn * 64;                 // this wave's 64-col half
  const bool ropeh = (cb % QK_DIM) == 512;     // rope region is 64-aligned, 64 wide
#pragma unroll
  for (int mi = 0; mi < 4; ++mi)
#pragma unroll
    for (int r = 0; r < 4; ++r) {
      int t = m0 + wm * 64 + mi * 16 + quad * 4 + r;
      if (ropeh) {
#pragma unroll
        for (int ni = 0; ni < 2; ++ni) {
          int d = ni * 16 + l16;
          float c0f = cosb[t * 64 + d], s0f = sinb[t * 64 + d];
          float c1f = cosb[t * 64 + d + 32], s1f = sinb[t * 64 + d + 32];
          float v1 = acc[mi][ni][r], v2 = acc[mi][ni + 2][r];
          qbuf[(size_t)t * QLD + cb + d] = f2bf(v1 * c0f - v2 * s0f);
          qbuf[(size_t)t * QLD + cb + 32 + d] = f2bf(v2 * c1f + v1 * s1f);
        }
      } else {
#pragma unroll
        for (int ni = 0; ni < 4; ++ni)
          qbuf[(size_t)t * QLD + cb + ni * 16 + l16] = f2bf(acc[mi][ni][r]);
      }
    }
}

// ================= 256x256 GEMM core, 3-barrier schedule (r7 config, best known) =========
// Geometry: BM=BN=256, BK=64, 8 waves (2M x 4N), 512 thr, 128 KiB LDS (2 dbuf x (A+B)).
// LDS regions (shorts): buf*32768 + r*8192, r = {0:A0(rows0-127), 1:A1, 2:B0, 3:B1},
// each [128 rows][64 cols] bf16 (128 B rows).
// 3-bit conflict-free swizzle (r5: SQ_LDS_BANK_CONFLICT 6.3M -> 0); 2-tile deep prefetch
// (r6); 3 barriers/K-tile (r7: 76.5 -> 70.9 us; hazard proof: BAR_B / BAR_A / BAR_T+vmcnt).
// REVERTED: r8 XCD chunking on out-proj (+6 us); r9 atomic epilogue (+53 us).
#define SWZ(o) ((o) ^ ((((o) >> 7) & 7) << 4))
#define SBAR() do { __builtin_amdgcn_s_barrier(); __builtin_amdgcn_sched_barrier(0); } while (0)
#define VMCNT(n) asm volatile("s_waitcnt vmcnt(" #n ")" ::: "memory")

__device__ __forceinline__ bf16x8_t frag_ld256(const unsigned short* region, int rl, int kk, int quad) {
  int lin = rl * 128 + kk * 64 + quad * 16;   // bytes within [128][64] bf16 region
  lin ^= (rl & 7) << 4;                       // 3-bit slot swizzle (conflict-free)
  return *(const bf16x8_t*)((const unsigned char*)region + lin);
}

// stage one half-tile: K-tile k, region r in {0:A0,1:A1,2:B0,3:B1}
__device__ __forceinline__ void stg256(
    const unsigned short* __restrict__ A, int lda, int m0,
    const unsigned short* __restrict__ Bt, int ldb, int n0,
    unsigned short* lds, int k, int r, int NT,
    int srow0, int scol0, int srow1, int scol1, int tid) {
  if (k >= NT) return;
  unsigned short* dst = lds + ((k & 1) << 15) + (r << 13);
  const unsigned short* g = (r < 2) ? A : Bt;
  const int ld = (r < 2) ? lda : ldb;
  const int rb = ((r < 2) ? m0 : n0) + (r & 1) * 128;
  const int c0 = k * 64;
  load_lds16(g + (size_t)(rb + srow0) * ld + c0 + scol0, dst + tid * 8);
  load_lds16(g + (size_t)(rb + srow1) * ld + c0 + scol1, dst + 4096 + tid * 8);
}

#define MFMAQ(MB, NB, BREG)                                                 \
  __builtin_amdgcn_s_setprio(1);                                            \
  _Pragma("unroll") for (int mi = 0; mi < 4; ++mi)                          \
    _Pragma("unroll") for (int ni = 0; ni < 2; ++ni)                        \
      _Pragma("unroll") for (int kk = 0; kk < 2; ++kk)                      \
        acc[(MB) + mi][(NB) + ni] = __builtin_amdgcn_mfma_f32_16x16x32_bf16( \
            a[mi][kk], BREG[ni][kk], acc[(MB) + mi][(NB) + ni], 0, 0, 0);    \
  __builtin_amdgcn_s_setprio(0);

#define STG(k, r) stg256(A, lda, m0, Bt, ldb, n0, lds, (k), (r), NT, srow0, scol0, srow1, scol1, tid)

__device__ __forceinline__ void kloop256(
    const unsigned short* __restrict__ A, int lda, int m0,
    const unsigned short* __restrict__ Bt, int ldb, int n0,
    int NT, unsigned short* lds, f32x4_t (&acc)[8][4],
    int tid, int quad, int l16, int wm, int wn) {
  // per-thread staging decode (fixed): LDS slot byte o -> swizzled source element
  const int o0 = tid * 16, o1 = 8192 + tid * 16;   // bytes within 16 KiB region
  const int so0 = SWZ(o0), so1 = SWZ(o1);
  const int srow0 = so0 >> 7, scol0 = (so0 & 127) >> 1;
  const int srow1 = so1 >> 7, scol1 = (so1 & 127) >> 1;
  // prologue: tiles 0 and 1 fully staged (16 loads); wait for tile0 (oldest 8)
  STG(0, 0); STG(0, 1); STG(0, 2); STG(0, 3);
  STG(1, 0); STG(1, 1); STG(1, 2); STG(1, 3);
  if (NT >= 2) { VMCNT(8); } else { VMCNT(0); }
  SBAR();
  const int brow = (wn & 1) * 64;
  for (int t = 0; t < NT; ++t) {
    const unsigned short* Ar = lds + ((t & 1) << 15) + (wm << 13);
    const unsigned short* Br = lds + ((t & 1) << 15) + 16384 + ((wn >> 1) << 13);
    bf16x8_t a[4][2], b0[2][2], b1[2][2];
    // ---- P1: a(mi0-3) + b0(ni0-1) [12 reads]; MFMA Q(0,0)   (no barrier)
#pragma unroll
    for (int mi = 0; mi < 4; ++mi) {
      a[mi][0] = frag_ld256(Ar, mi * 16 + l16, 0, quad);
      a[mi][1] = frag_ld256(Ar, mi * 16 + l16, 1, quad);
    }
#pragma unroll
    for (int ni = 0; ni < 2; ++ni) {
      b0[ni][0] = frag_ld256(Br, brow + ni * 16 + l16, 0, quad);
      b0[ni][1] = frag_ld256(Br, brow + ni * 16 + l16, 1, quad);
    }
    MFMAQ(0, 0, b0);
    // ---- P2: b1(ni2-3) [4 reads]; MFMA Q(0,2); BAR_B (all B reads drained chip-wide)
#pragma unroll
    for (int ni = 0; ni < 2; ++ni) {
      b1[ni][0] = frag_ld256(Br, brow + (2 + ni) * 16 + l16, 0, quad);
      b1[ni][1] = frag_ld256(Br, brow + (2 + ni) * 16 + l16, 1, quad);
    }
    MFMAQ(0, 2, b1);
    SBAR();
    // ---- P3: a(mi4-7) [8 reads, overwrite a]; stage (t+2).B0,B1 (safe post-BAR_B);
    //          MFMA Q(4,2); BAR_A (all A reads drained chip-wide)
#pragma unroll
    for (int mi = 0; mi < 4; ++mi) {
      a[mi][0] = frag_ld256(Ar, (4 + mi) * 16 + l16, 0, quad);
      a[mi][1] = frag_ld256(Ar, (4 + mi) * 16 + l16, 1, quad);
    }
    STG(t + 2, 2); STG(t + 2, 3);
    MFMAQ(4, 2, b1);
    SBAR();
    // ---- P4: stage (t+2).A0,A1 (safe post-BAR_A); MFMA Q(4,0); vmcnt; BAR_T
    STG(t + 2, 0); STG(t + 2, 1);
    MFMAQ(4, 0, b0);
    if (t < NT - 2) { VMCNT(8); }
    else if (t == NT - 2) { VMCNT(0); }
    SBAR();
  }
}

// ---------------- 256^2 split-K GEMM: out-projection (default mapping, partials) ----------
__global__ __launch_bounds__(512, 2) void gemm256_splitk(
    const unsigned short* __restrict__ A, int lda,
    const unsigned short* __restrict__ Bt, int ldb,
    float* __restrict__ P, int ldc, int Ks) {
  __shared__ __align__(16) unsigned short lds[65536];   // 128 KiB
  const int tid = threadIdx.x;
  const int quad = (tid >> 4) & 3, l16 = tid & 15;
  const int wave = tid >> 6, wm = wave >> 2, wn = wave & 3;
  const int m0 = blockIdx.y * 256, n0 = blockIdx.x * 256;
  const unsigned short* Ap = A + (size_t)blockIdx.z * Ks;
  const unsigned short* Bp = Bt + (size_t)blockIdx.z * Ks;
  float* C = P + (size_t)blockIdx.z * ((size_t)gridDim.y * 256) * ldc;
  f32x4_t acc[8][4];
  f32x4_t z4 = {0.f, 0.f, 0.f, 0.f};
#pragma unroll
  for (int mi = 0; mi < 8; ++mi)
#pragma unroll
    for (int ni = 0; ni < 4; ++ni) acc[mi][ni] = z4;
  kloop256(Ap, lda, m0, Bp, ldb, n0, Ks >> 6, lds, acc, tid, quad, l16, wm, wn);
#pragma unroll
  for (int mi = 0; mi < 8; ++mi)
#pragma unroll
    for (int ni = 0; ni < 4; ++ni)
#pragma unroll
      for (int r = 0; r < 4; ++r) {
        const int row = m0 + wm * 128 + mi * 16 + quad * 4 + r;
        const int col = n0 + wn * 64 + ni * 16 + l16;
        C[(size_t)row * ldc + col] = acc[mi][ni][r];
      }
}

// ---------------- split-K reduction (final) ----------------
__global__ __launch_bounds__(256) void reduce4_f32(const float* __restrict__ p,
                                                   float* __restrict__ dst, int n) {
  int i = (blockIdx.x * 256 + threadIdx.x) * 4;
  if (i < n) {
    float4 a = *(const float4*)&p[i];
    float4 b = *(const float4*)&p[(size_t)n + i];
    float4 c = *(const float4*)&p[2 * (size_t)n + i];
    float4 d = *(const float4*)&p[3 * (size_t)n + i];
    float4 o;
    o.x = (a.x + b.x) + (c.x + d.x);
    o.y = (a.y + b.y) + (c.y + d.y);
    o.z = (a.z + b.z) + (c.z + d.z);
    o.w = (a.w + b.w) + (c.w + d.w);
    *(float4*)&dst[i] = o;
  }
}

// ---------------- QK^T + exp pass, 256x256 tiles on the 256^2 3-barrier core (r11) --------
// Per head: 256-row q-tiles ig=0..7, key-tiles j=0..ig -> 36 tiles/head, 288 blocks/panel.
// XCD chunk: 288 = 8 x 36 -> XCD k gets EXACTLY head k's 36 tiles (q-panel 2.36 MB
// L2-resident; kbuf shared via L3). Heavy-ig-first within each head.
// E layout (256-granular packed): per head, tile (ig,j) lives at
//   Ebuf + (hl*36 + ig(ig+1)/2)*65536, row-major [256][Kmax=(ig+1)*256]; causal-invalid
//   entries stored as 0 -> PV over the coarser Kmax is exact.
__global__ __launch_bounds__(512, 2) void qke256_kernel(
    const unsigned short* __restrict__ qbuf,
    const unsigned short* __restrict__ kbuf,
    unsigned short* __restrict__ Ebuf,
    float* __restrict__ lsum, int hbase) {
  __shared__ __align__(16) unsigned short lds[65536];   // 128 KiB
  const int tid = threadIdx.x;
  const int quad = (tid >> 4) & 3, l16 = tid & 15;
  const int wave = tid >> 6, wm = wave >> 2, wn = wave & 3;
  const int id = blockIdx.x + 36 * blockIdx.y;        // grid (36,8)
  const int wg = (id & 7) * 36 + (id >> 3);           // bijective 288=8*36 (1 head/XCD)
  int tx = wg % 36;
  const int hl = wg / 36;
  int ig = 7, cnt = 8;
  while (tx >= cnt) { tx -= cnt; --ig; --cnt; }       // heavy-first
  const int j = tx;                                   // key tile (256 keys)
  const int h = hbase + hl;
  const int Kmax = (ig + 1) << 8;
  const int pre = (ig * (ig + 1)) >> 1;

  const unsigned short* A = qbuf + (size_t)(ig << 8) * QLD + h * QK_DIM;  // 256 q-rows
  const unsigned short* Bt = kbuf + (size_t)(j << 8) * KLD;               // 256 keys
  unsigned short* Eh = Ebuf + ((size_t)hl * 36 + pre) * 65536;

  f32x4_t acc[8][4];
  f32x4_t z4 = {0.f, 0.f, 0.f, 0.f};
#pragma unroll
  for (int mi = 0; mi < 8; ++mi)
#pragma unroll
    for (int ni = 0; ni < 4; ++ni) acc[mi][ni] = z4;
  kloop256(A, QLD, 0, Bt, KLD, 0, QK_DIM >> 6, lds, acc, tid, quad, l16, wm, wn);

#pragma unroll
  for (int mi = 0; mi < 8; ++mi) {
    float rs[4] = {0.f, 0.f, 0.f, 0.f};
#pragma unroll
    for (int ni = 0; ni < 4; ++ni)
#pragma unroll
      for (int r = 0; r < 4; ++r) {
        const int rloc = wm * 128 + mi * 16 + quad * 4 + r;     // [0,256)
        const int row_g = (ig << 8) + rloc;                     // global q row
        const int key = (j << 8) + wn * 64 + ni * 16 + l16;     // global key
        float e = (key <= row_g) ? __expf(acc[mi][ni][r] * SCALE) : 0.f;
        rs[r] += e;
        Eh[(size_t)rloc * Kmax + key] = f2bf(e);
      }
#pragma unroll
    for (int r = 0; r < 4; ++r) {
      float s = rs[r];
#pragma unroll
      for (int off = 1; off < 16; off <<= 1) s += __shfl_xor(s, off, 64);
      if (l16 == 0) {
        const int row_g = (ig << 8) + wm * 128 + mi * 16 + quad * 4 + r;
        atomicAdd(&lsum[h * TSEQ + row_g], s);
      }
    }
  }
}

// ---------------- PV pass: y = (E @ V) / rowsum (reads 256-granular E) ----------------
// XCD-chunked: 512 = 8 x 64 -> one head per XCD. qt = 128-row tile (heavy first);
// ig = qt>>1 selects the 256-tile, sub = qt&1 the 128-row slice within it.
__global__ __launch_bounds__(256, 2) void pv_kernel(
    const unsigned short* __restrict__ Ebuf,
    const unsigned short* __restrict__ vtg,
    const float* __restrict__ lsum,
    unsigned short* __restrict__ ybuf, int hbase) {
  const int id = blockIdx.x + 4 * blockIdx.y + 64 * blockIdx.z;  // grid (4,16,8)
  const int wg = (id & 7) * 64 + (id >> 3);                      // bijective 512=8*64
  const int qt = 15 - ((wg >> 2) & 15);    // 128-row tile, heavy first
  const int hl = wg >> 6, h = hbase + hl;
  const int n0 = (wg & 3) * 128;
  const int ig = qt >> 1, sub = qt & 1;
  const int Kmax = (ig + 1) << 8;
  const int pre = (ig * (ig + 1)) >> 1;

  const unsigned short* A = Ebuf + ((size_t)hl * 36 + pre) * 65536
                          + (size_t)sub * 128 * Kmax;

  GEMM_PROLOGUE();
  GEMM_KLOOP(A, Kmax, vtg, TSEQ, 0, n0, Kmax);

#pragma unroll
  for (int mi = 0; mi < 4; ++mi)
#pragma unroll
    for (int r = 0; r < 4; ++r) {
      int row_g = (qt << 7) + wm * 64 + mi * 16 + quad * 4 + r;
      float inv = 1.f / lsum[h * TSEQ + row_g];
#pragma unroll
      for (int ni = 0; ni < 4; ++ni) {
        int col = h * V_DIM + n0 + wn * 64 + ni * 16 + l16;
        ybuf[(size_t)row_g * YLD + col] = f2bf(acc[mi][ni][r] * inv);
      }
    }
}

// ---------------- launch ----------------
extern "C" void kernel_launch(void* const* d_in, const int* in_sizes, int n_in,
                              void* d_out, int out_size, void* d_ws, size_t ws_size,
                              hipStream_t stream) {
  (void)in_sizes; (void)n_in; (void)out_size; (void)ws_size;
  const float* x     = (const float*)d_in[0];
  const float* cosb  = (const float*)d_in[1];
  const float* sinb  = (const float*)d_in[2];
  const float* wqkv  = (const float*)d_in[3];
  const float* wqdec = (const float*)d_in[4];
  const float* wout  = (const float*)d_in[5];
  float* out = (float*)d_out;

  // ws layout (shorts). [xb, wqkvT, wqdecT, lat] dead by attention time -> Ebuf alias.
  unsigned short* ws     = (unsigned short*)d_ws;
  unsigned short* xb     = ws;                                  //  4,194,304
  unsigned short* wqkvT  = xb     + (size_t)2048 * 2048;        //  3,407,872
  unsigned short* wqdecT = wqkvT  + (size_t)1664 * 2048;        //  9,437,184
  unsigned short* lat    = wqdecT + (size_t)9216 * 1024;        //  3,407,872  (ends 20,447,232)
  unsigned short* qbuf   = lat    + (size_t)2048 * 1664;        // 18,874,368  (ends 39,321,600)
  unsigned short* woutT  = qbuf   + (size_t)2048 * 9216;        // 16,777,216
  unsigned short* ybuf   = woutT  + (size_t)2048 * 8192;        // 16,777,216
  unsigned short* vtg    = ybuf   + (size_t)2048 * 8192;        //  1,048,576
  unsigned short* kbuf   = vtg    + (size_t)512 * 2048;         //  1,179,648
  float*          lsumf  = (float*)(kbuf + (size_t)2048 * 576); //     32,768 floats
  // aliases:
  unsigned short* Ebuf   = ws;            // 8 heads x 36 tiles x 65536 = 18.87M shorts <= 20.45M
  float*          P1     = (float*)qbuf;  // gemm1 partials: 6.82M floats <= 9.44M
  float*          Pf     = (float*)ws;    // final partials: 16.78M floats <= 19.66M (thru qbuf)

  prep_all<<<11360, 256, 0, stream>>>(x, xb, wqkv, wqkvT, wqdec, wqdecT, wout, woutT, lsumf);

  // latents = x @ W_qkv  (split-K x2 -> fp32 partials)
  gemm_splitk<<<dim3(13, 16, 2), 256, 0, stream>>>(xb, 2048, wqkvT, 2048, P1, 1664, 1024);
  // fused: reduce partials + RoPE-K -> kbuf, V-transpose -> vtg, c_q -> lat
  postlat<<<dim3(32, 26), 256, 0, stream>>>(P1, lat, kbuf, vtg, cosb, sinb);

  // q = rope(c_q @ W_qdec)  -> bf16 [2048][9216]  (128^2 core, balanced 1152-block grid)
  gemm_qdec<<<dim3(72, 16), 256, 0, stream>>>(lat + 576, wqdecT, qbuf, cosb, sinb);

  // attention: 2 head-panels of 8 heads each; 256-granular packed-causal E
  qke256_kernel<<<dim3(36, 8), 512, 0, stream>>>(qbuf, kbuf, Ebuf, lsumf, 0);
  pv_kernel<<<dim3(4, 16, 8), 256, 0, stream>>>(Ebuf, vtg, lsumf, ybuf, 0);
  qke256_kernel<<<dim3(36, 8), 512, 0, stream>>>(qbuf, kbuf, Ebuf, lsumf, 8);
  pv_kernel<<<dim3(4, 16, 8), 256, 0, stream>>>(Ebuf, vtg, lsumf, ybuf, 8);

  // out = y @ W_out  (256^2 3-barrier core, split-K x4 -> fp32 partials -> fp32 out)
  gemm256_splitk<<<dim3(8, 8, 4), 512, 0, stream>>>(ybuf, 8192, woutT, 8192, Pf, 2048, 2048);
  reduce4_f32<<<4096, 256, 0, stream>>>(Pf, out, 2048 * 2048);
}

// Round 12
// 483.171 us; speedup vs baseline: 1.1184x; 1.1184x over previous
//
#include <hip/hip_runtime.h>

typedef __bf16 bf16x8_t __attribute__((ext_vector_type(8)));
typedef float f32x4_t __attribute__((ext_vector_type(4)));

#define LAT_LD 1664
#define QK_DIM 576
#define V_DIM 512
#define NHEAD 16
#define TSEQ 2048
#define QLD 9216
#define YLD 8192
#define KLD 576
#define SCALE 0.044194173824159216f

__device__ __forceinline__ unsigned short f2bf(float f) {
  union { float f; unsigned int u; } v; v.f = f;
  unsigned int r = v.u + 0x7FFFu + ((v.u >> 16) & 1u);
  return (unsigned short)(r >> 16);
}

// async global->LDS 16B (m97 pattern). LDS dest must be wave-uniform base + lane*16.
__device__ __forceinline__ void load_lds16(const unsigned short* g, unsigned short* l) {
  __builtin_amdgcn_global_load_lds((const __attribute__((address_space(1))) void*)g,
                                   (__attribute__((address_space(3))) void*)l, 16, 0, 0);
}

// ---------------- fused prep: x->bf16, 3x transpose-convert, lsum zero ----------------
__device__ __forceinline__ void conv_t_body(const float* __restrict__ src, int R, int Csrc,
                                            unsigned short* __restrict__ dst,
                                            int bx, int by, int tid,
                                            unsigned short (*T)[72]) {
  const int r0 = bx * 64, c0 = by * 64;
  const bool live = (c0 < Csrc);
#pragma unroll
  for (int it = 0; it < 4; ++it) {
    int idx = it * 256 + tid;
    int r = idx >> 4, c4 = (idx & 15) * 4;   // row-contiguous: coalesced fp32 reads
    float4 v = {0.f, 0.f, 0.f, 0.f};
    if (live) v = *(const float4*)&src[(size_t)(r0 + r) * Csrc + c0 + c4];
    T[c4 + 0][r] = f2bf(v.x);
    T[c4 + 1][r] = f2bf(v.y);
    T[c4 + 2][r] = f2bf(v.z);
    T[c4 + 3][r] = f2bf(v.w);
  }
  __syncthreads();
#pragma unroll
  for (int it = 0; it < 2; ++it) {
    int idx = it * 256 + tid;
    int cc = idx >> 3, r8 = (idx & 7) * 8;
    uint4 v = *(const uint4*)&T[cc][r8];
    *(uint4*)&dst[(size_t)(c0 + cc) * R + r0 + r8] = v;
  }
}

// jobs: [0,4096) conv x; [4096,4928) wqkvT; [4928,7232) wqdecT; [7232,11328) woutT;
//       [11328,11360) zero lsum
__global__ __launch_bounds__(256) void prep_all(
    const float* __restrict__ x, unsigned short* __restrict__ xb,
    const float* __restrict__ wqkv, unsigned short* __restrict__ wqkvT,
    const float* __restrict__ wqdec, unsigned short* __restrict__ wqdecT,
    const float* __restrict__ wout, unsigned short* __restrict__ woutT,
    float* __restrict__ lsum) {
  __shared__ unsigned short T[64][72];
  const int blk = blockIdx.x, tid = threadIdx.x;
  if (blk < 4096) {
    int i = (blk * 256 + tid) * 4;
    float4 v = *(const float4*)&x[i];
    ushort4 o;
    o.x = f2bf(v.x); o.y = f2bf(v.y); o.z = f2bf(v.z); o.w = f2bf(v.w);
    *(ushort4*)&xb[i] = o;
  } else if (blk < 4928) {
    int l = blk - 4096;
    conv_t_body(wqkv, 2048, 1600, wqkvT, l & 31, l >> 5, tid, T);
  } else if (blk < 7232) {
    int l = blk - 4928;
    conv_t_body(wqdec, 1024, 9216, wqdecT, l & 15, l >> 4, tid, T);
  } else if (blk < 11328) {
    int l = blk - 7232;
    conv_t_body(wout, 8192, 2048, woutT, l & 127, l >> 7, tid, T);
  } else {
    int i = ((blk - 11328) * 256 + tid) * 4;
    *(float4*)&lsum[i] = (float4){0.f, 0.f, 0.f, 0.f};
  }
}

// ---------------- fused post-gemm1: reduce split-K partials + RoPE-K + V-transpose ----------------
__global__ __launch_bounds__(256) void postlat(
    const float* __restrict__ P1,
    unsigned short* __restrict__ lat,
    unsigned short* __restrict__ kbuf,
    unsigned short* __restrict__ vtg,
    const float* __restrict__ cosb, const float* __restrict__ sinb) {
  __shared__ unsigned short T[64][72];
  const int tid = threadIdx.x;
  const int bx = blockIdx.x, by = blockIdx.y;
  const int r0 = bx * 64, c0 = by * 64;
  const size_t n = (size_t)2048 * 1664;

#pragma unroll
  for (int it = 0; it < 4; ++it) {
    int idx = it * 256 + tid;
    int r = idx >> 4, c4 = (idx & 15) * 4;
    size_t off = (size_t)(r0 + r) * 1664 + c0 + c4;
    float4 a = *(const float4*)&P1[off];
    float4 b = *(const float4*)&P1[n + off];
    ushort4 o;
    o.x = f2bf(a.x + b.x); o.y = f2bf(a.y + b.y);
    o.z = f2bf(a.z + b.z); o.w = f2bf(a.w + b.w);
    if (by < 8) {
      *(ushort4*)&kbuf[(size_t)(r0 + r) * KLD + c0 + c4] = o;
      T[c4 + 0][r] = o.x; T[c4 + 1][r] = o.y; T[c4 + 2][r] = o.z; T[c4 + 3][r] = o.w;
    } else if (by == 8) {
      T[r][c4 + 0] = o.x; T[r][c4 + 1] = o.y; T[r][c4 + 2] = o.z; T[r][c4 + 3] = o.w;
    } else {
      *(ushort4*)&lat[(size_t)(r0 + r) * LAT_LD + c0 + c4] = o;
    }
  }
  if (by > 8) return;
  __syncthreads();
  if (by < 8) {
#pragma unroll
    for (int it = 0; it < 2; ++it) {
      int idx = it * 256 + tid;
      int cc = idx >> 3, r8 = (idx & 7) * 8;
      uint4 v = *(const uint4*)&T[cc][r8];
      *(uint4*)&vtg[(size_t)(c0 + cc) * TSEQ + r0 + r8] = v;
    }
  } else {
#pragma unroll
    for (int it = 0; it < 8; ++it) {
      int idx = it * 256 + tid;
      int r = idx >> 5, d = idx & 31;
      int t = r0 + r;
      union { unsigned int u; float f; } a, b;
      a.u = ((unsigned int)T[r][d]) << 16;
      b.u = ((unsigned int)T[r][d + 32]) << 16;
      float c0f = cosb[t * 64 + d], s0f = sinb[t * 64 + d];
      float c1f = cosb[t * 64 + d + 32], s1f = sinb[t * 64 + d + 32];
      kbuf[(size_t)t * KLD + 512 + d] = f2bf(a.f * c0f - b.f * s0f);
      kbuf[(size_t)t * KLD + 544 + d] = f2bf(b.f * c1f + a.f * s1f);
    }
  }
}

// ---------------- m97-style GEMM core, BK=64 (gemm1 / qdec / qke / pv) ----------------
#define GEMM_PROLOGUE()                                                     \
  __shared__ __align__(16) unsigned short As[8192];                         \
  __shared__ __align__(16) unsigned short Bs[8192];                         \
  const int tid = threadIdx.x;                                              \
  const int wave = tid >> 6, lane = tid & 63;                               \
  const int quad = lane >> 4, l16 = lane & 15;                              \
  const int wm = wave >> 1, wn = wave & 1;                                  \
  f32x4_t acc[4][4];                                                        \
  f32x4_t zero = {0.f, 0.f, 0.f, 0.f};                                      \
  _Pragma("unroll") for (int mi = 0; mi < 4; ++mi)                          \
    _Pragma("unroll") for (int ni = 0; ni < 4; ++ni) acc[mi][ni] = zero;

#define GEMM_KLOOP(Aptr, Alda, Bptr, Bldb, M0, N0, KLEN)                    \
  for (int k0 = 0; k0 < (KLEN); k0 += 64) {                                 \
    _Pragma("unroll") for (int p2 = 0; p2 < 2; ++p2) {                      \
      int ci = p2 * 256 + tid;                                              \
      int rr2 = ci >> 2, cc2 = (ci & 3) * 8;                                \
      const unsigned short* ga = &(Aptr)[(size_t)((M0) + rr2) * (Alda) + k0 + cc2]; \
      const unsigned short* gb = &(Bptr)[(size_t)((N0) + rr2) * (Bldb) + k0 + cc2]; \
      load_lds16(ga,      &As[ci * 8]);                                     \
      load_lds16(ga + 32, &As[4096 + ci * 8]);                              \
      load_lds16(gb,      &Bs[ci * 8]);                                     \
      load_lds16(gb + 32, &Bs[4096 + ci * 8]);                              \
    }                                                                       \
    __syncthreads();                                                        \
    _Pragma("unroll") for (int hf = 0; hf < 2; ++hf) {                      \
      bf16x8_t af[4], bfr[4];                                               \
      _Pragma("unroll") for (int mi = 0; mi < 4; ++mi)                      \
        af[mi] = *(const bf16x8_t*)&As[hf * 4096 + (wm * 64 + mi * 16 + l16) * 32 + quad * 8]; \
      _Pragma("unroll") for (int ni = 0; ni < 4; ++ni)                      \
        bfr[ni] = *(const bf16x8_t*)&Bs[hf * 4096 + (wn * 64 + ni * 16 + l16) * 32 + quad * 8]; \
      _Pragma("unroll") for (int mi = 0; mi < 4; ++mi)                      \
        _Pragma("unroll") for (int ni = 0; ni < 4; ++ni)                    \
          acc[mi][ni] = __builtin_amdgcn_mfma_f32_16x16x32_bf16(af[mi], bfr[ni], acc[mi][ni], 0, 0, 0); \
    }                                                                       \
    __syncthreads();                                                        \
  }

// ---------------- split-K GEMM (128^2, used for gemm1) ----------------
__global__ __launch_bounds__(256, 2) void gemm_splitk(
    const unsigned short* __restrict__ A, int lda,
    const unsigned short* __restrict__ Bt, int ldb,
    float* __restrict__ P, int ldc, int Ks) {
  const int m0 = blockIdx.y * 128, n0 = blockIdx.x * 128;
  const size_t koff = (size_t)blockIdx.z * Ks;
  const unsigned short* Ap = A + koff;
  const unsigned short* Bp = Bt + koff;
  float* C = P + (size_t)blockIdx.z * ((size_t)gridDim.y * 128) * ldc;
  GEMM_PROLOGUE();
  GEMM_KLOOP(Ap, lda, Bp, ldb, m0, n0, Ks);
#pragma unroll
  for (int mi = 0; mi < 4; ++mi)
#pragma unroll
    for (int ni = 0; ni < 4; ++ni)
#pragma unroll
      for (int r = 0; r < 4; ++r) {
        int row = m0 + wm * 64 + mi * 16 + quad * 4 + r;
        int col = n0 + wn * 64 + ni * 16 + l16;
        C[(size_t)row * ldc + col] = acc[mi][ni][r];
      }
}

// ---------------- gemm2 with fused RoPE-q epilogue (128^2 core, balanced grid) ------------
__global__ __launch_bounds__(256, 2) void gemm_qdec(
    const unsigned short* __restrict__ A,      // lat + 576 (c_q), lda LAT_LD
    const unsigned short* __restrict__ Bt,     // wqdecT [9216][1024]
    unsigned short* __restrict__ qbuf,
    const float* __restrict__ cosb, const float* __restrict__ sinb) {
  const int m0 = blockIdx.y * 128, n0 = blockIdx.x * 128;
  GEMM_PROLOGUE();
  GEMM_KLOOP(A, LAT_LD, Bt, 1024, m0, n0, 1024);

  const int cb = n0 + wn * 64;                 // this wave's 64-col half
  const bool ropeh = (cb % QK_DIM) == 512;     // rope region is 64-aligned, 64 wide
#pragma unroll
  for (int mi = 0; mi < 4; ++mi)
#pragma unroll
    for (int r = 0; r < 4; ++r) {
      int t = m0 + wm * 64 + mi * 16 + quad * 4 + r;
      if (ropeh) {
#pragma unroll
        for (int ni = 0; ni < 2; ++ni) {
          int d = ni * 16 + l16;
          float c0f = cosb[t * 64 + d], s0f = sinb[t * 64 + d];
          float c1f = cosb[t * 64 + d + 32], s1f = sinb[t * 64 + d + 32];
          float v1 = acc[mi][ni][r], v2 = acc[mi][ni + 2][r];
          qbuf[(size_t)t * QLD + cb + d] = f2bf(v1 * c0f - v2 * s0f);
          qbuf[(size_t)t * QLD + cb + 32 + d] = f2bf(v2 * c1f + v1 * s1f);
        }
      } else {
#pragma unroll
        for (int ni = 0; ni < 4; ++ni)
          qbuf[(size_t)t * QLD + cb + ni * 16 + l16] = f2bf(acc[mi][ni][r]);
      }
    }
}

// ================= 256x256 GEMM core, 3-barrier schedule (r7 config, best known) =========
// Geometry: BM=BN=256, BK=64, 8 waves (2M x 4N), 512 thr, 128 KiB LDS (2 dbuf x (A+B)).
// LDS regions (shorts): buf*32768 + r*8192, r = {0:A0(rows0-127), 1:A1, 2:B0, 3:B1},
// each [128 rows][64 cols] bf16 (128 B rows).
// 3-bit conflict-free swizzle (r5: SQ_LDS_BANK_CONFLICT 6.3M -> 0); 2-tile deep prefetch
// (r6); 3 barriers/K-tile (r7: 76.5 -> 70.9 us; hazard proof: BAR_B / BAR_A / BAR_T+vmcnt).
// REVERTED: r8 XCD chunk on out-proj (+6 us); r9 atomics (+53 us); r11 qke256 (+76 us:
// 288-block 1/CU imbalance + unhidden epilogue).
#define SWZ(o) ((o) ^ ((((o) >> 7) & 7) << 4))
#define SBAR() do { __builtin_amdgcn_s_barrier(); __builtin_amdgcn_sched_barrier(0); } while (0)
#define VMCNT(n) asm volatile("s_waitcnt vmcnt(" #n ")" ::: "memory")

__device__ __forceinline__ bf16x8_t frag_ld256(const unsigned short* region, int rl, int kk, int quad) {
  int lin = rl * 128 + kk * 64 + quad * 16;   // bytes within [128][64] bf16 region
  lin ^= (rl & 7) << 4;                       // 3-bit slot swizzle (conflict-free)
  return *(const bf16x8_t*)((const unsigned char*)region + lin);
}

// stage one half-tile: K-tile k, region r in {0:A0,1:A1,2:B0,3:B1}
__device__ __forceinline__ void stg256(
    const unsigned short* __restrict__ A, int lda, int m0,
    const unsigned short* __restrict__ Bt, int ldb, int n0,
    unsigned short* lds, int k, int r, int NT,
    int srow0, int scol0, int srow1, int scol1, int tid) {
  if (k >= NT) return;
  unsigned short* dst = lds + ((k & 1) << 15) + (r << 13);
  const unsigned short* g = (r < 2) ? A : Bt;
  const int ld = (r < 2) ? lda : ldb;
  const int rb = ((r < 2) ? m0 : n0) + (r & 1) * 128;
  const int c0 = k * 64;
  load_lds16(g + (size_t)(rb + srow0) * ld + c0 + scol0, dst + tid * 8);
  load_lds16(g + (size_t)(rb + srow1) * ld + c0 + scol1, dst + 4096 + tid * 8);
}

#define MFMAQ(MB, NB, BREG)                                                 \
  __builtin_amdgcn_s_setprio(1);                                            \
  _Pragma("unroll") for (int mi = 0; mi < 4; ++mi)                          \
    _Pragma("unroll") for (int ni = 0; ni < 2; ++ni)                        \
      _Pragma("unroll") for (int kk = 0; kk < 2; ++kk)                      \
        acc[(MB) + mi][(NB) + ni] = __builtin_amdgcn_mfma_f32_16x16x32_bf16( \
            a[mi][kk], BREG[ni][kk], acc[(MB) + mi][(NB) + ni], 0, 0, 0);    \
  __builtin_amdgcn_s_setprio(0);

#define STG(k, r) stg256(A, lda, m0, Bt, ldb, n0, lds, (k), (r), NT, srow0, scol0, srow1, scol1, tid)

__device__ __forceinline__ void kloop256(
    const unsigned short* __restrict__ A, int lda, int m0,
    const unsigned short* __restrict__ Bt, int ldb, int n0,
    int NT, unsigned short* lds, f32x4_t (&acc)[8][4],
    int tid, int quad, int l16, int wm, int wn) {
  // per-thread staging decode (fixed): LDS slot byte o -> swizzled source element
  const int o0 = tid * 16, o1 = 8192 + tid * 16;   // bytes within 16 KiB region
  const int so0 = SWZ(o0), so1 = SWZ(o1);
  const int srow0 = so0 >> 7, scol0 = (so0 & 127) >> 1;
  const int srow1 = so1 >> 7, scol1 = (so1 & 127) >> 1;
  // prologue: tiles 0 and 1 fully staged (16 loads); wait for tile0 (oldest 8)
  STG(0, 0); STG(0, 1); STG(0, 2); STG(0, 3);
  STG(1, 0); STG(1, 1); STG(1, 2); STG(1, 3);
  if (NT >= 2) { VMCNT(8); } else { VMCNT(0); }
  SBAR();
  const int brow = (wn & 1) * 64;
  for (int t = 0; t < NT; ++t) {
    const unsigned short* Ar = lds + ((t & 1) << 15) + (wm << 13);
    const unsigned short* Br = lds + ((t & 1) << 15) + 16384 + ((wn >> 1) << 13);
    bf16x8_t a[4][2], b0[2][2], b1[2][2];
    // ---- P1: a(mi0-3) + b0(ni0-1) [12 reads]; MFMA Q(0,0)   (no barrier)
#pragma unroll
    for (int mi = 0; mi < 4; ++mi) {
      a[mi][0] = frag_ld256(Ar, mi * 16 + l16, 0, quad);
      a[mi][1] = frag_ld256(Ar, mi * 16 + l16, 1, quad);
    }
#pragma unroll
    for (int ni = 0; ni < 2; ++ni) {
      b0[ni][0] = frag_ld256(Br, brow + ni * 16 + l16, 0, quad);
      b0[ni][1] = frag_ld256(Br, brow + ni * 16 + l16, 1, quad);
    }
    MFMAQ(0, 0, b0);
    // ---- P2: b1(ni2-3) [4 reads]; MFMA Q(0,2); BAR_B (all B reads drained chip-wide)
#pragma unroll
    for (int ni = 0; ni < 2; ++ni) {
      b1[ni][0] = frag_ld256(Br, brow + (2 + ni) * 16 + l16, 0, quad);
      b1[ni][1] = frag_ld256(Br, brow + (2 + ni) * 16 + l16, 1, quad);
    }
    MFMAQ(0, 2, b1);
    SBAR();
    // ---- P3: a(mi4-7) [8 reads, overwrite a]; stage (t+2).B0,B1 (safe post-BAR_B);
    //          MFMA Q(4,2); BAR_A (all A reads drained chip-wide)
#pragma unroll
    for (int mi = 0; mi < 4; ++mi) {
      a[mi][0] = frag_ld256(Ar, (4 + mi) * 16 + l16, 0, quad);
      a[mi][1] = frag_ld256(Ar, (4 + mi) * 16 + l16, 1, quad);
    }
    STG(t + 2, 2); STG(t + 2, 3);
    MFMAQ(4, 2, b1);
    SBAR();
    // ---- P4: stage (t+2).A0,A1 (safe post-BAR_A); MFMA Q(4,0); vmcnt; BAR_T
    STG(t + 2, 0); STG(t + 2, 1);
    MFMAQ(4, 0, b0);
    if (t < NT - 2) { VMCNT(8); }
    else if (t == NT - 2) { VMCNT(0); }
    SBAR();
  }
}

// ---------------- 256^2 split-K GEMM: out-projection (default mapping, partials) ----------
__global__ __launch_bounds__(512, 2) void gemm256_splitk(
    const unsigned short* __restrict__ A, int lda,
    const unsigned short* __restrict__ Bt, int ldb,
    float* __restrict__ P, int ldc, int Ks) {
  __shared__ __align__(16) unsigned short lds[65536];   // 128 KiB
  const int tid = threadIdx.x;
  const int quad = (tid >> 4) & 3, l16 = tid & 15;
  const int wave = tid >> 6, wm = wave >> 2, wn = wave & 3;
  const int m0 = blockIdx.y * 256, n0 = blockIdx.x * 256;
  const unsigned short* Ap = A + (size_t)blockIdx.z * Ks;
  const unsigned short* Bp = Bt + (size_t)blockIdx.z * Ks;
  float* C = P + (size_t)blockIdx.z * ((size_t)gridDim.y * 256) * ldc;
  f32x4_t acc[8][4];
  f32x4_t z4 = {0.f, 0.f, 0.f, 0.f};
#pragma unroll
  for (int mi = 0; mi < 8; ++mi)
#pragma unroll
    for (int ni = 0; ni < 4; ++ni) acc[mi][ni] = z4;
  kloop256(Ap, lda, m0, Bp, ldb, n0, Ks >> 6, lds, acc, tid, quad, l16, wm, wn);
#pragma unroll
  for (int mi = 0; mi < 8; ++mi)
#pragma unroll
    for (int ni = 0; ni < 4; ++ni)
#pragma unroll
      for (int r = 0; r < 4; ++r) {
        const int row = m0 + wm * 128 + mi * 16 + quad * 4 + r;
        const int col = n0 + wn * 64 + ni * 16 + l16;
        C[(size_t)row * ldc + col] = acc[mi][ni][r];
      }
}

// ---------------- split-K reduction (final) ----------------
__global__ __launch_bounds__(256) void reduce4_f32(const float* __restrict__ p,
                                                   float* __restrict__ dst, int n) {
  int i = (blockIdx.x * 256 + threadIdx.x) * 4;
  if (i < n) {
    float4 a = *(const float4*)&p[i];
    float4 b = *(const float4*)&p[(size_t)n + i];
    float4 c = *(const float4*)&p[2 * (size_t)n + i];
    float4 d = *(const float4*)&p[3 * (size_t)n + i];
    float4 o;
    o.x = (a.x + b.x) + (c.x + d.x);
    o.y = (a.y + b.y) + (c.y + d.y);
    o.z = (a.z + b.z) + (c.z + d.z);
    o.w = (a.w + b.w) + (c.w + d.w);
    *(float4*)&dst[i] = o;
  }
}

// ---------------- QK^T + exp pass for 8 heads, all 16 q-tiles, packed-causal E ----------------
// XCD-chunked (r10, kept): 1088 = 8 x 136 -> one head per XCD; per-block work is constant
// (NT=9) so no pairing needed.
__global__ __launch_bounds__(256, 2) void qke_kernel(
    const unsigned short* __restrict__ qbuf,
    const unsigned short* __restrict__ kbuf,
    unsigned short* __restrict__ Ebuf,
    float* __restrict__ lsum, int hbase) {
  const int id = blockIdx.x + 136 * blockIdx.y;       // grid (136,8)
  const int wg = (id & 7) * 136 + (id >> 3);          // bijective 1088=8*136
  int tx = wg % 136;
  const int hl = wg / 136;
  int ig = 15, cnt = 16;
  while (tx >= cnt) { tx -= cnt; --ig; --cnt; }
  const int j = tx;                       // key tile
  const int h = hbase + hl;
  const int Kmax = (ig + 1) << 7;
  const int r0g = ig << 7;
  const int pre = (ig * (ig + 1)) >> 1;

  const unsigned short* A = qbuf + (size_t)r0g * QLD + h * QK_DIM;
  const unsigned short* Bt = kbuf + (size_t)(j << 7) * KLD;
  unsigned short* Eh = Ebuf + ((size_t)hl * 136 + pre) * 16384;

  GEMM_PROLOGUE();
  GEMM_KLOOP(A, QLD, Bt, KLD, 0, 0, QK_DIM);

#pragma unroll
  for (int mi = 0; mi < 4; ++mi) {
    float rs[4] = {0.f, 0.f, 0.f, 0.f};
#pragma unroll
    for (int ni = 0; ni < 4; ++ni)
#pragma unroll
      for (int r = 0; r < 4; ++r) {
        int qr = r0g + wm * 64 + mi * 16 + quad * 4 + r;
        int key = (j << 7) + wn * 64 + ni * 16 + l16;
        float e = (key <= qr) ? __expf(acc[mi][ni][r] * SCALE) : 0.f;
        rs[r] += e;
        Eh[(size_t)(qr - r0g) * Kmax + key] = f2bf(e);
      }
#pragma unroll
    for (int r = 0; r < 4; ++r) {
      float s = rs[r];
#pragma unroll
      for (int off = 1; off < 16; off <<= 1) s += __shfl_xor(s, off, 64);
      if (l16 == 0) {
        int qr = r0g + wm * 64 + mi * 16 + quad * 4 + r;
        atomicAdd(&lsum[h * TSEQ + qr], s);
      }
    }
  }
}

// ---------------- PV pass: y = (E @ V) / rowsum ----------------
// XCD-chunked + COMPLEMENT-PAIRED (r12): 512 = 8 x 64, one head per XCD. With 2 blocks/CU,
// HW pairs block id with id+256 (same chunk, local l and l+32) on one CU. Decode:
//   l <  32: ig = 15 - (l>>1), n0 = (l&1)*128      (heavy, n-tiles 0-1)
//   l >= 32: ig = (l-32)>>1,   n0 = ((l&1)+2)*128  (light, n-tiles 2-3)
// Pair (l, l+32): NT sum = (16-k)+(k+1) = 17 K-tile units per CU, constant -> removes the
// 64-vs-17-unit critical-CU imbalance of the old heavy-first order (both-heavy pairing).
__global__ __launch_bounds__(256, 2) void pv_kernel(
    const unsigned short* __restrict__ Ebuf,
    const unsigned short* __restrict__ vtg,
    const float* __restrict__ lsum,
    unsigned short* __restrict__ ybuf, int hbase) {
  const int id = blockIdx.x + 4 * blockIdx.y + 64 * blockIdx.z;  // grid (4,16,8)
  const int wg = (id & 7) * 64 + (id >> 3);                      // bijective 512=8*64
  const int hl = wg >> 6, h = hbase + hl;
  const int l = wg & 63;
  int ig, n0;
  if (l < 32) { ig = 15 - (l >> 1); n0 = (l & 1) * 128; }
  else        { ig = (l - 32) >> 1; n0 = ((l & 1) + 2) * 128; }
  const int Kmax = (ig + 1) << 7;
  const int pre = (ig * (ig + 1)) >> 1;

  const unsigned short* A = Ebuf + ((size_t)hl * 136 + pre) * 16384;

  GEMM_PROLOGUE();
  GEMM_KLOOP(A, Kmax, vtg, TSEQ, 0, n0, Kmax);

#pragma unroll
  for (int mi = 0; mi < 4; ++mi)
#pragma unroll
    for (int r = 0; r < 4; ++r) {
      int row_g = (ig << 7) + wm * 64 + mi * 16 + quad * 4 + r;
      float inv = 1.f / lsum[h * TSEQ + row_g];
#pragma unroll
      for (int ni = 0; ni < 4; ++ni) {
        int col = h * V_DIM + n0 + wn * 64 + ni * 16 + l16;
        ybuf[(size_t)row_g * YLD + col] = f2bf(acc[mi][ni][r] * inv);
      }
    }
}

// ---------------- launch ----------------
extern "C" void kernel_launch(void* const* d_in, const int* in_sizes, int n_in,
                              void* d_out, int out_size, void* d_ws, size_t ws_size,
                              hipStream_t stream) {
  (void)in_sizes; (void)n_in; (void)out_size; (void)ws_size;
  const float* x     = (const float*)d_in[0];
  const float* cosb  = (const float*)d_in[1];
  const float* sinb  = (const float*)d_in[2];
  const float* wqkv  = (const float*)d_in[3];
  const float* wqdec = (const float*)d_in[4];
  const float* wout  = (const float*)d_in[5];
  float* out = (float*)d_out;

  // ws layout (shorts). [xb, wqkvT, wqdecT, lat] dead by attention time -> Ebuf alias.
  unsigned short* ws     = (unsigned short*)d_ws;
  unsigned short* xb     = ws;                                  //  4,194,304
  unsigned short* wqkvT  = xb     + (size_t)2048 * 2048;        //  3,407,872
  unsigned short* wqdecT = wqkvT  + (size_t)1664 * 2048;        //  9,437,184
  unsigned short* lat    = wqdecT + (size_t)9216 * 1024;        //  3,407,872  (ends 20,447,232)
  unsigned short* qbuf   = lat    + (size_t)2048 * 1664;        // 18,874,368  (ends 39,321,600)
  unsigned short* woutT  = qbuf   + (size_t)2048 * 9216;        // 16,777,216
  unsigned short* ybuf   = woutT  + (size_t)2048 * 8192;        // 16,777,216
  unsigned short* vtg    = ybuf   + (size_t)2048 * 8192;        //  1,048,576
  unsigned short* kbuf   = vtg    + (size_t)512 * 2048;         //  1,179,648
  float*          lsumf  = (float*)(kbuf + (size_t)2048 * 576); //     32,768 floats
  // aliases:
  unsigned short* Ebuf   = ws;            // 8 heads x 136 tiles x 16384 = 17.83M shorts <= 20.45M
  float*          P1     = (float*)qbuf;  // gemm1 partials: 6.82M floats <= 9.44M
  float*          Pf     = (float*)ws;    // final partials: 16.78M floats <= 19.66M (thru qbuf)

  prep_all<<<11360, 256, 0, stream>>>(x, xb, wqkv, wqkvT, wqdec, wqdecT, wout, woutT, lsumf);

  // latents = x @ W_qkv  (split-K x2 -> fp32 partials)
  gemm_splitk<<<dim3(13, 16, 2), 256, 0, stream>>>(xb, 2048, wqkvT, 2048, P1, 1664, 1024);
  // fused: reduce partials + RoPE-K -> kbuf, V-transpose -> vtg, c_q -> lat
  postlat<<<dim3(32, 26), 256, 0, stream>>>(P1, lat, kbuf, vtg, cosb, sinb);

  // q = rope(c_q @ W_qdec)  -> bf16 [2048][9216]  (128^2 core, balanced 1152-block grid)
  gemm_qdec<<<dim3(72, 16), 256, 0, stream>>>(lat + 576, wqdecT, qbuf, cosb, sinb);

  // attention: 2 head-panels of 8 heads each; packed-causal E; XCD head-chunked grids
  qke_kernel<<<dim3(136, 8), 256, 0, stream>>>(qbuf, kbuf, Ebuf, lsumf, 0);
  pv_kernel<<<dim3(4, 16, 8), 256, 0, stream>>>(Ebuf, vtg, lsumf, ybuf, 0);
  qke_kernel<<<dim3(136, 8), 256, 0, stream>>>(qbuf, kbuf, Ebuf, lsumf, 8);
  pv_kernel<<<dim3(4, 16, 8), 256, 0, stream>>>(Ebuf, vtg, lsumf, ybuf, 8);

  // out = y @ W_out  (256^2 3-barrier core, split-K x4 -> fp32 partials -> fp32 out)
  gemm256_splitk<<<dim3(8, 8, 4), 512, 0, stream>>>(ybuf, 8192, woutT, 8192, Pf, 2048, 2048);
  reduce4_f32<<<4096, 256, 0, stream>>>(Pf, out, 2048 * 2048);
}

// Round 14
// 471.417 us; speedup vs baseline: 1.1463x; 1.0249x over previous
//
#include <hip/hip_runtime.h>

typedef __bf16 bf16x8_t __attribute__((ext_vector_type(8)));
typedef float f32x4_t __attribute__((ext_vector_type(4)));

#define LAT_LD 1664
#define QK_DIM 576
#define V_DIM 512
#define NHEAD 16
#define TSEQ 2048
#define QLD 9216
#define YLD 8192
#define KLD 576
#define SCALE 0.044194173824159216f

__device__ __forceinline__ unsigned short f2bf(float f) {
  union { float f; unsigned int u; } v; v.f = f;
  unsigned int r = v.u + 0x7FFFu + ((v.u >> 16) & 1u);
  return (unsigned short)(r >> 16);
}

// async global->LDS 16B (m97 pattern). LDS dest must be wave-uniform base + lane*16.
__device__ __forceinline__ void load_lds16(const unsigned short* g, unsigned short* l) {
  __builtin_amdgcn_global_load_lds((const __attribute__((address_space(1))) void*)g,
                                   (__attribute__((address_space(3))) void*)l, 16, 0, 0);
}

// ---------------- fused prep: x->bf16, 3x transpose-convert, lsum zero ----------------
__device__ __forceinline__ void conv_t_body(const float* __restrict__ src, int R, int Csrc,
                                            unsigned short* __restrict__ dst,
                                            int bx, int by, int tid,
                                            unsigned short (*T)[72]) {
  const int r0 = bx * 64, c0 = by * 64;
  const bool live = (c0 < Csrc);
#pragma unroll
  for (int it = 0; it < 4; ++it) {
    int idx = it * 256 + tid;
    int r = idx >> 4, c4 = (idx & 15) * 4;   // row-contiguous: coalesced fp32 reads
    float4 v = {0.f, 0.f, 0.f, 0.f};
    if (live) v = *(const float4*)&src[(size_t)(r0 + r) * Csrc + c0 + c4];
    T[c4 + 0][r] = f2bf(v.x);
    T[c4 + 1][r] = f2bf(v.y);
    T[c4 + 2][r] = f2bf(v.z);
    T[c4 + 3][r] = f2bf(v.w);
  }
  __syncthreads();
#pragma unroll
  for (int it = 0; it < 2; ++it) {
    int idx = it * 256 + tid;
    int cc = idx >> 3, r8 = (idx & 7) * 8;
    uint4 v = *(const uint4*)&T[cc][r8];
    *(uint4*)&dst[(size_t)(c0 + cc) * R + r0 + r8] = v;
  }
}

// jobs: [0,4096) conv x; [4096,4928) wqkvT; [4928,7232) wqdecT; [7232,11328) woutT;
//       [11328,11360) zero lsum
__global__ __launch_bounds__(256) void prep_all(
    const float* __restrict__ x, unsigned short* __restrict__ xb,
    const float* __restrict__ wqkv, unsigned short* __restrict__ wqkvT,
    const float* __restrict__ wqdec, unsigned short* __restrict__ wqdecT,
    const float* __restrict__ wout, unsigned short* __restrict__ woutT,
    float* __restrict__ lsum) {
  __shared__ unsigned short T[64][72];
  const int blk = blockIdx.x, tid = threadIdx.x;
  if (blk < 4096) {
    int i = (blk * 256 + tid) * 4;
    float4 v = *(const float4*)&x[i];
    ushort4 o;
    o.x = f2bf(v.x); o.y = f2bf(v.y); o.z = f2bf(v.z); o.w = f2bf(v.w);
    *(ushort4*)&xb[i] = o;
  } else if (blk < 4928) {
    int l = blk - 4096;
    conv_t_body(wqkv, 2048, 1600, wqkvT, l & 31, l >> 5, tid, T);
  } else if (blk < 7232) {
    int l = blk - 4928;
    conv_t_body(wqdec, 1024, 9216, wqdecT, l & 15, l >> 4, tid, T);
  } else if (blk < 11328) {
    int l = blk - 7232;
    conv_t_body(wout, 8192, 2048, woutT, l & 127, l >> 7, tid, T);
  } else {
    int i = ((blk - 11328) * 256 + tid) * 4;
    *(float4*)&lsum[i] = (float4){0.f, 0.f, 0.f, 0.f};
  }
}

// ---------------- fused post-gemm1: reduce split-K partials + RoPE-K + V-transpose ----------------
__global__ __launch_bounds__(256) void postlat(
    const float* __restrict__ P1,
    unsigned short* __restrict__ lat,
    unsigned short* __restrict__ kbuf,
    unsigned short* __restrict__ vtg,
    const float* __restrict__ cosb, const float* __restrict__ sinb) {
  __shared__ unsigned short T[64][72];
  const int tid = threadIdx.x;
  const int bx = blockIdx.x, by = blockIdx.y;
  const int r0 = bx * 64, c0 = by * 64;
  const size_t n = (size_t)2048 * 1664;

#pragma unroll
  for (int it = 0; it < 4; ++it) {
    int idx = it * 256 + tid;
    int r = idx >> 4, c4 = (idx & 15) * 4;
    size_t off = (size_t)(r0 + r) * 1664 + c0 + c4;
    float4 a = *(const float4*)&P1[off];
    float4 b = *(const float4*)&P1[n + off];
    ushort4 o;
    o.x = f2bf(a.x + b.x); o.y = f2bf(a.y + b.y);
    o.z = f2bf(a.z + b.z); o.w = f2bf(a.w + b.w);
    if (by < 8) {
      *(ushort4*)&kbuf[(size_t)(r0 + r) * KLD + c0 + c4] = o;
      T[c4 + 0][r] = o.x; T[c4 + 1][r] = o.y; T[c4 + 2][r] = o.z; T[c4 + 3][r] = o.w;
    } else if (by == 8) {
      T[r][c4 + 0] = o.x; T[r][c4 + 1] = o.y; T[r][c4 + 2] = o.z; T[r][c4 + 3] = o.w;
    } else {
      *(ushort4*)&lat[(size_t)(r0 + r) * LAT_LD + c0 + c4] = o;
    }
  }
  if (by > 8) return;
  __syncthreads();
  if (by < 8) {
#pragma unroll
    for (int it = 0; it < 2; ++it) {
      int idx = it * 256 + tid;
      int cc = idx >> 3, r8 = (idx & 7) * 8;
      uint4 v = *(const uint4*)&T[cc][r8];
      *(uint4*)&vtg[(size_t)(c0 + cc) * TSEQ + r0 + r8] = v;
    }
  } else {
#pragma unroll
    for (int it = 0; it < 8; ++it) {
      int idx = it * 256 + tid;
      int r = idx >> 5, d = idx & 31;
      int t = r0 + r;
      union { unsigned int u; float f; } a, b;
      a.u = ((unsigned int)T[r][d]) << 16;
      b.u = ((unsigned int)T[r][d + 32]) << 16;
      float c0f = cosb[t * 64 + d], s0f = sinb[t * 64 + d];
      float c1f = cosb[t * 64 + d + 32], s1f = sinb[t * 64 + d + 32];
      kbuf[(size_t)t * KLD + 512 + d] = f2bf(a.f * c0f - b.f * s0f);
      kbuf[(size_t)t * KLD + 544 + d] = f2bf(b.f * c1f + a.f * s1f);
    }
  }
}

// ---------------- m97-style GEMM core, BK=64 (gemm1 / qdec / qke / pv) ----------------
#define GEMM_PROLOGUE()                                                     \
  __shared__ __align__(16) unsigned short As[8192];                         \
  __shared__ __align__(16) unsigned short Bs[8192];                         \
  const int tid = threadIdx.x;                                              \
  const int wave = tid >> 6, lane = tid & 63;                               \
  const int quad = lane >> 4, l16 = lane & 15;                              \
  const int wm = wave >> 1, wn = wave & 1;                                  \
  f32x4_t acc[4][4];                                                        \
  f32x4_t zero = {0.f, 0.f, 0.f, 0.f};                                      \
  _Pragma("unroll") for (int mi = 0; mi < 4; ++mi)                          \
    _Pragma("unroll") for (int ni = 0; ni < 4; ++ni) acc[mi][ni] = zero;

#define GEMM_KLOOP(Aptr, Alda, Bptr, Bldb, M0, N0, KLEN)                    \
  for (int k0 = 0; k0 < (KLEN); k0 += 64) {                                 \
    _Pragma("unroll") for (int p2 = 0; p2 < 2; ++p2) {                      \
      int ci = p2 * 256 + tid;                                              \
      int rr2 = ci >> 2, cc2 = (ci & 3) * 8;                                \
      const unsigned short* ga = &(Aptr)[(size_t)((M0) + rr2) * (Alda) + k0 + cc2]; \
      const unsigned short* gb = &(Bptr)[(size_t)((N0) + rr2) * (Bldb) + k0 + cc2]; \
      load_lds16(ga,      &As[ci * 8]);                                     \
      load_lds16(ga + 32, &As[4096 + ci * 8]);                              \
      load_lds16(gb,      &Bs[ci * 8]);                                     \
      load_lds16(gb + 32, &Bs[4096 + ci * 8]);                              \
    }                                                                       \
    __syncthreads();                                                        \
    _Pragma("unroll") for (int hf = 0; hf < 2; ++hf) {                      \
      bf16x8_t af[4], bfr[4];                                               \
      _Pragma("unroll") for (int mi = 0; mi < 4; ++mi)                      \
        af[mi] = *(const bf16x8_t*)&As[hf * 4096 + (wm * 64 + mi * 16 + l16) * 32 + quad * 8]; \
      _Pragma("unroll") for (int ni = 0; ni < 4; ++ni)                      \
        bfr[ni] = *(const bf16x8_t*)&Bs[hf * 4096 + (wn * 64 + ni * 16 + l16) * 32 + quad * 8]; \
      _Pragma("unroll") for (int mi = 0; mi < 4; ++mi)                      \
        _Pragma("unroll") for (int ni = 0; ni < 4; ++ni)                    \
          acc[mi][ni] = __builtin_amdgcn_mfma_f32_16x16x32_bf16(af[mi], bfr[ni], acc[mi][ni], 0, 0, 0); \
    }                                                                       \
    __syncthreads();                                                        \
  }

// ---------------- split-K GEMM (128^2, used for gemm1) ----------------
__global__ __launch_bounds__(256, 2) void gemm_splitk(
    const unsigned short* __restrict__ A, int lda,
    const unsigned short* __restrict__ Bt, int ldb,
    float* __restrict__ P, int ldc, int Ks) {
  const int m0 = blockIdx.y * 128, n0 = blockIdx.x * 128;
  const size_t koff = (size_t)blockIdx.z * Ks;
  const unsigned short* Ap = A + koff;
  const unsigned short* Bp = Bt + koff;
  float* C = P + (size_t)blockIdx.z * ((size_t)gridDim.y * 128) * ldc;
  GEMM_PROLOGUE();
  GEMM_KLOOP(Ap, lda, Bp, ldb, m0, n0, Ks);
#pragma unroll
  for (int mi = 0; mi < 4; ++mi)
#pragma unroll
    for (int ni = 0; ni < 4; ++ni)
#pragma unroll
      for (int r = 0; r < 4; ++r) {
        int row = m0 + wm * 64 + mi * 16 + quad * 4 + r;
        int col = n0 + wn * 64 + ni * 16 + l16;
        C[(size_t)row * ldc + col] = acc[mi][ni][r];
      }
}

// ---------------- gemm2 with fused RoPE-q epilogue (128^2 core, balanced grid) ------------
__global__ __launch_bounds__(256, 2) void gemm_qdec(
    const unsigned short* __restrict__ A,      // lat + 576 (c_q), lda LAT_LD
    const unsigned short* __restrict__ Bt,     // wqdecT [9216][1024]
    unsigned short* __restrict__ qbuf,
    const float* __restrict__ cosb, const float* __restrict__ sinb) {
  const int m0 = blockIdx.y * 128, n0 = blockIdx.x * 128;
  GEMM_PROLOGUE();
  GEMM_KLOOP(A, LAT_LD, Bt, 1024, m0, n0, 1024);

  const int cb = n0 + wn * 64;                 // this wave's 64-col half
  const bool ropeh = (cb % QK_DIM) == 512;     // rope region is 64-aligned, 64 wide
#pragma unroll
  for (int mi = 0; mi < 4; ++mi)
#pragma unroll
    for (int r = 0; r < 4; ++r) {
      int t = m0 + wm * 64 + mi * 16 + quad * 4 + r;
      if (ropeh) {
#pragma unroll
        for (int ni = 0; ni < 2; ++ni) {
          int d = ni * 16 + l16;
          float c0f = cosb[t * 64 + d], s0f = sinb[t * 64 + d];
          float c1f = cosb[t * 64 + d + 32], s1f = sinb[t * 64 + d + 32];
          float v1 = acc[mi][ni][r], v2 = acc[mi][ni + 2][r];
          qbuf[(size_t)t * QLD + cb + d] = f2bf(v1 * c0f - v2 * s0f);
          qbuf[(size_t)t * QLD + cb + 32 + d] = f2bf(v2 * c1f + v1 * s1f);
        }
      } else {
#pragma unroll
        for (int ni = 0; ni < 4; ++ni)
          qbuf[(size_t)t * QLD + cb + ni * 16 + l16] = f2bf(acc[mi][ni][r]);
      }
    }
}

// ================= 256x256 GEMM core, 3-barrier schedule (r7 config, best known) =========
// Geometry: BM=BN=256, BK=64, 8 waves (2M x 4N), 512 thr, 128 KiB LDS (2 dbuf x (A+B)).
// LDS regions (shorts): buf*32768 + r*8192, r = {0:A0(rows0-127), 1:A1, 2:B0, 3:B1},
// each [128 rows][64 cols] bf16 (128 B rows).
// 3-bit conflict-free swizzle (r5: SQ_LDS_BANK_CONFLICT 6.3M -> 0); 2-tile deep prefetch
// (r6); 3 barriers/K-tile (r7: 76.5 -> 70.9 us; hazard proof: BAR_B / BAR_A / BAR_T+vmcnt).
// REVERTED: r8 XCD chunk on out-proj (+6 us); r9 atomics (+53 us); r11 qke256 (+76 us).
#define SWZ(o) ((o) ^ ((((o) >> 7) & 7) << 4))
#define SBAR() do { __builtin_amdgcn_s_barrier(); __builtin_amdgcn_sched_barrier(0); } while (0)
#define VMCNT(n) asm volatile("s_waitcnt vmcnt(" #n ")" ::: "memory")

__device__ __forceinline__ bf16x8_t frag_ld256(const unsigned short* region, int rl, int kk, int quad) {
  int lin = rl * 128 + kk * 64 + quad * 16;   // bytes within [128][64] bf16 region
  lin ^= (rl & 7) << 4;                       // 3-bit slot swizzle (conflict-free)
  return *(const bf16x8_t*)((const unsigned char*)region + lin);
}

// stage one half-tile: K-tile k, region r in {0:A0,1:A1,2:B0,3:B1}
__device__ __forceinline__ void stg256(
    const unsigned short* __restrict__ A, int lda, int m0,
    const unsigned short* __restrict__ Bt, int ldb, int n0,
    unsigned short* lds, int k, int r, int NT,
    int srow0, int scol0, int srow1, int scol1, int tid) {
  if (k >= NT) return;
  unsigned short* dst = lds + ((k & 1) << 15) + (r << 13);
  const unsigned short* g = (r < 2) ? A : Bt;
  const int ld = (r < 2) ? lda : ldb;
  const int rb = ((r < 2) ? m0 : n0) + (r & 1) * 128;
  const int c0 = k * 64;
  load_lds16(g + (size_t)(rb + srow0) * ld + c0 + scol0, dst + tid * 8);
  load_lds16(g + (size_t)(rb + srow1) * ld + c0 + scol1, dst + 4096 + tid * 8);
}

#define MFMAQ(MB, NB, BREG)                                                 \
  __builtin_amdgcn_s_setprio(1);                                            \
  _Pragma("unroll") for (int mi = 0; mi < 4; ++mi)                          \
    _Pragma("unroll") for (int ni = 0; ni < 2; ++ni)                        \
      _Pragma("unroll") for (int kk = 0; kk < 2; ++kk)                      \
        acc[(MB) + mi][(NB) + ni] = __builtin_amdgcn_mfma_f32_16x16x32_bf16( \
            a[mi][kk], BREG[ni][kk], acc[(MB) + mi][(NB) + ni], 0, 0, 0);    \
  __builtin_amdgcn_s_setprio(0);

#define STG(k, r) stg256(A, lda, m0, Bt, ldb, n0, lds, (k), (r), NT, srow0, scol0, srow1, scol1, tid)

__device__ __forceinline__ void kloop256(
    const unsigned short* __restrict__ A, int lda, int m0,
    const unsigned short* __restrict__ Bt, int ldb, int n0,
    int NT, unsigned short* lds, f32x4_t (&acc)[8][4],
    int tid, int quad, int l16, int wm, int wn) {
  // per-thread staging decode (fixed): LDS slot byte o -> swizzled source element
  const int o0 = tid * 16, o1 = 8192 + tid * 16;   // bytes within 16 KiB region
  const int so0 = SWZ(o0), so1 = SWZ(o1);
  const int srow0 = so0 >> 7, scol0 = (so0 & 127) >> 1;
  const int srow1 = so1 >> 7, scol1 = (so1 & 127) >> 1;
  // prologue: tiles 0 and 1 fully staged (16 loads); wait for tile0 (oldest 8)
  STG(0, 0); STG(0, 1); STG(0, 2); STG(0, 3);
  STG(1, 0); STG(1, 1); STG(1, 2); STG(1, 3);
  if (NT >= 2) { VMCNT(8); } else { VMCNT(0); }
  SBAR();
  const int brow = (wn & 1) * 64;
  for (int t = 0; t < NT; ++t) {
    const unsigned short* Ar = lds + ((t & 1) << 15) + (wm << 13);
    const unsigned short* Br = lds + ((t & 1) << 15) + 16384 + ((wn >> 1) << 13);
    bf16x8_t a[4][2], b0[2][2], b1[2][2];
    // ---- P1: a(mi0-3) + b0(ni0-1) [12 reads]; MFMA Q(0,0)   (no barrier)
#pragma unroll
    for (int mi = 0; mi < 4; ++mi) {
      a[mi][0] = frag_ld256(Ar, mi * 16 + l16, 0, quad);
      a[mi][1] = frag_ld256(Ar, mi * 16 + l16, 1, quad);
    }
#pragma unroll
    for (int ni = 0; ni < 2; ++ni) {
      b0[ni][0] = frag_ld256(Br, brow + ni * 16 + l16, 0, quad);
      b0[ni][1] = frag_ld256(Br, brow + ni * 16 + l16, 1, quad);
    }
    MFMAQ(0, 0, b0);
    // ---- P2: b1(ni2-3) [4 reads]; MFMA Q(0,2); BAR_B (all B reads drained chip-wide)
#pragma unroll
    for (int ni = 0; ni < 2; ++ni) {
      b1[ni][0] = frag_ld256(Br, brow + (2 + ni) * 16 + l16, 0, quad);
      b1[ni][1] = frag_ld256(Br, brow + (2 + ni) * 16 + l16, 1, quad);
    }
    MFMAQ(0, 2, b1);
    SBAR();
    // ---- P3: a(mi4-7) [8 reads, overwrite a]; stage (t+2).B0,B1 (safe post-BAR_B);
    //          MFMA Q(4,2); BAR_A (all A reads drained chip-wide)
#pragma unroll
    for (int mi = 0; mi < 4; ++mi) {
      a[mi][0] = frag_ld256(Ar, (4 + mi) * 16 + l16, 0, quad);
      a[mi][1] = frag_ld256(Ar, (4 + mi) * 16 + l16, 1, quad);
    }
    STG(t + 2, 2); STG(t + 2, 3);
    MFMAQ(4, 2, b1);
    SBAR();
    // ---- P4: stage (t+2).A0,A1 (safe post-BAR_A); MFMA Q(4,0); vmcnt; BAR_T
    STG(t + 2, 0); STG(t + 2, 1);
    MFMAQ(4, 0, b0);
    if (t < NT - 2) { VMCNT(8); }
    else if (t == NT - 2) { VMCNT(0); }
    SBAR();
  }
}

// ---------------- 256^2 split-K GEMM: out-projection (default mapping, partials) ----------
__global__ __launch_bounds__(512, 2) void gemm256_splitk(
    const unsigned short* __restrict__ A, int lda,
    const unsigned short* __restrict__ Bt, int ldb,
    float* __restrict__ P, int ldc, int Ks) {
  __shared__ __align__(16) unsigned short lds[65536];   // 128 KiB
  const int tid = threadIdx.x;
  const int quad = (tid >> 4) & 3, l16 = tid & 15;
  const int wave = tid >> 6, wm = wave >> 2, wn = wave & 3;
  const int m0 = blockIdx.y * 256, n0 = blockIdx.x * 256;
  const unsigned short* Ap = A + (size_t)blockIdx.z * Ks;
  const unsigned short* Bp = Bt + (size_t)blockIdx.z * Ks;
  float* C = P + (size_t)blockIdx.z * ((size_t)gridDim.y * 256) * ldc;
  f32x4_t acc[8][4];
  f32x4_t z4 = {0.f, 0.f, 0.f, 0.f};
#pragma unroll
  for (int mi = 0; mi < 8; ++mi)
#pragma unroll
    for (int ni = 0; ni < 4; ++ni) acc[mi][ni] = z4;
  kloop256(Ap, lda, m0, Bp, ldb, n0, Ks >> 6, lds, acc, tid, quad, l16, wm, wn);
#pragma unroll
  for (int mi = 0; mi < 8; ++mi)
#pragma unroll
    for (int ni = 0; ni < 4; ++ni)
#pragma unroll
      for (int r = 0; r < 4; ++r) {
        const int row = m0 + wm * 128 + mi * 16 + quad * 4 + r;
        const int col = n0 + wn * 64 + ni * 16 + l16;
        C[(size_t)row * ldc + col] = acc[mi][ni][r];
      }
}

// ---------------- split-K reduction (final) ----------------
__global__ __launch_bounds__(256) void reduce4_f32(const float* __restrict__ p,
                                                   float* __restrict__ dst, int n) {
  int i = (blockIdx.x * 256 + threadIdx.x) * 4;
  if (i < n) {
    float4 a = *(const float4*)&p[i];
    float4 b = *(const float4*)&p[(size_t)n + i];
    float4 c = *(const float4*)&p[2 * (size_t)n + i];
    float4 d = *(const float4*)&p[3 * (size_t)n + i];
    float4 o;
    o.x = (a.x + b.x) + (c.x + d.x);
    o.y = (a.y + b.y) + (c.y + d.y);
    o.z = (a.z + b.z) + (c.z + d.z);
    o.w = (a.w + b.w) + (c.w + d.w);
    *(float4*)&dst[i] = o;
  }
}

// ---------------- QK^T + exp pass for 8 heads, all 16 q-tiles, packed-causal E ----------------
// XCD-chunked (r10, kept): 1088 = 8 x 136 -> one head per XCD; per-block work is constant
// (NT=9) so no pairing needed.
__global__ __launch_bounds__(256, 2) void qke_kernel(
    const unsigned short* __restrict__ qbuf,
    const unsigned short* __restrict__ kbuf,
    unsigned short* __restrict__ Ebuf,
    float* __restrict__ lsum, int hbase) {
  const int id = blockIdx.x + 136 * blockIdx.y;       // grid (136,8)
  const int wg = (id & 7) * 136 + (id >> 3);          // bijective 1088=8*136
  int tx = wg % 136;
  const int hl = wg / 136;
  int ig = 15, cnt = 16;
  while (tx >= cnt) { tx -= cnt; --ig; --cnt; }
  const int j = tx;                       // key tile
  const int h = hbase + hl;
  const int Kmax = (ig + 1) << 7;
  const int r0g = ig << 7;
  const int pre = (ig * (ig + 1)) >> 1;

  const unsigned short* A = qbuf + (size_t)r0g * QLD + h * QK_DIM;
  const unsigned short* Bt = kbuf + (size_t)(j << 7) * KLD;
  unsigned short* Eh = Ebuf + ((size_t)hl * 136 + pre) * 16384;

  GEMM_PROLOGUE();
  GEMM_KLOOP(A, QLD, Bt, KLD, 0, 0, QK_DIM);

#pragma unroll
  for (int mi = 0; mi < 4; ++mi) {
    float rs[4] = {0.f, 0.f, 0.f, 0.f};
#pragma unroll
    for (int ni = 0; ni < 4; ++ni)
#pragma unroll
      for (int r = 0; r < 4; ++r) {
        int qr = r0g + wm * 64 + mi * 16 + quad * 4 + r;
        int key = (j << 7) + wn * 64 + ni * 16 + l16;
        float e = (key <= qr) ? __expf(acc[mi][ni][r] * SCALE) : 0.f;
        rs[r] += e;
        Eh[(size_t)(qr - r0g) * Kmax + key] = f2bf(e);
      }
#pragma unroll
    for (int r = 0; r < 4; ++r) {
      float s = rs[r];
#pragma unroll
      for (int off = 1; off < 16; off <<= 1) s += __shfl_xor(s, off, 64);
      if (l16 == 0) {
        int qr = r0g + wm * 64 + mi * 16 + quad * 4 + r;
        atomicAdd(&lsum[h * TSEQ + qr], s);
      }
    }
  }
}

// ---------------- PV pass: y = (E @ V) / rowsum ----------------
// XCD-chunked + ADJACENT-complement-paired (r13): 512 = 8 x 64, one head per XCD.
// r12 tested complement under (l, l+32) CU-pairing -> null. This round tests the
// transpose hypothesis: HW pairs CONSECUTIVE blocks (2m, 2m+1) on a CU. Decode:
//   m = l>>1, p = l&1, jj = m&7, n0 = (m>>3)*128, ig = p ? jj : 15-jj
// Bijective (m = (n0/128)*8 + jj unique; p splits heavy/light). Adjacent pair (2m,2m+1)
// covers ig = {15-jj, jj} -> NT sum = (16-jj)+(jj+1) = 17 units constant per CU.
// If null too: pv is not pairing-imbalance-bound; decomposition at structural floor.
__global__ __launch_bounds__(256, 2) void pv_kernel(
    const unsigned short* __restrict__ Ebuf,
    const unsigned short* __restrict__ vtg,
    const float* __restrict__ lsum,
    unsigned short* __restrict__ ybuf, int hbase) {
  const int id = blockIdx.x + 4 * blockIdx.y + 64 * blockIdx.z;  // grid (4,16,8)
  const int wg = (id & 7) * 64 + (id >> 3);                      // bijective 512=8*64
  const int hl = wg >> 6, h = hbase + hl;
  const int l = wg & 63;
  const int m = l >> 1, p = l & 1;
  const int jj = m & 7;
  const int n0 = (m >> 3) * 128;
  const int ig = p ? jj : 15 - jj;
  const int Kmax = (ig + 1) << 7;
  const int pre = (ig * (ig + 1)) >> 1;

  const unsigned short* A = Ebuf + ((size_t)hl * 136 + pre) * 16384;

  GEMM_PROLOGUE();
  GEMM_KLOOP(A, Kmax, vtg, TSEQ, 0, n0, Kmax);

#pragma unroll
  for (int mi = 0; mi < 4; ++mi)
#pragma unroll
    for (int r = 0; r < 4; ++r) {
      int row_g = (ig << 7) + wm * 64 + mi * 16 + quad * 4 + r;
      float inv = 1.f / lsum[h * TSEQ + row_g];
#pragma unroll
      for (int ni = 0; ni < 4; ++ni) {
        int col = h * V_DIM + n0 + wn * 64 + ni * 16 + l16;
        ybuf[(size_t)row_g * YLD + col] = f2bf(acc[mi][ni][r] * inv);
      }
    }
}

// ---------------- launch ----------------
extern "C" void kernel_launch(void* const* d_in, const int* in_sizes, int n_in,
                              void* d_out, int out_size, void* d_ws, size_t ws_size,
                              hipStream_t stream) {
  (void)in_sizes; (void)n_in; (void)out_size; (void)ws_size;
  const float* x     = (const float*)d_in[0];
  const float* cosb  = (const float*)d_in[1];
  const float* sinb  = (const float*)d_in[2];
  const float* wqkv  = (const float*)d_in[3];
  const float* wqdec = (const float*)d_in[4];
  const float* wout  = (const float*)d_in[5];
  float* out = (float*)d_out;

  // ws layout (shorts). [xb, wqkvT, wqdecT, lat] dead by attention time -> Ebuf alias.
  unsigned short* ws     = (unsigned short*)d_ws;
  unsigned short* xb     = ws;                                  //  4,194,304
  unsigned short* wqkvT  = xb     + (size_t)2048 * 2048;        //  3,407,872
  unsigned short* wqdecT = wqkvT  + (size_t)1664 * 2048;        //  9,437,184
  unsigned short* lat    = wqdecT + (size_t)9216 * 1024;        //  3,407,872  (ends 20,447,232)
  unsigned short* qbuf   = lat    + (size_t)2048 * 1664;        // 18,874,368  (ends 39,321,600)
  unsigned short* woutT  = qbuf   + (size_t)2048 * 9216;        // 16,777,216
  unsigned short* ybuf   = woutT  + (size_t)2048 * 8192;        // 16,777,216
  unsigned short* vtg    = ybuf   + (size_t)2048 * 8192;        //  1,048,576
  unsigned short* kbuf   = vtg    + (size_t)512 * 2048;         //  1,179,648
  float*          lsumf  = (float*)(kbuf + (size_t)2048 * 576); //     32,768 floats
  // aliases:
  unsigned short* Ebuf   = ws;            // 8 heads x 136 tiles x 16384 = 17.83M shorts <= 20.45M
  float*          P1     = (float*)qbuf;  // gemm1 partials: 6.82M floats <= 9.44M
  float*          Pf     = (float*)ws;    // final partials: 16.78M floats <= 19.66M (thru qbuf)

  prep_all<<<11360, 256, 0, stream>>>(x, xb, wqkv, wqkvT, wqdec, wqdecT, wout, woutT, lsumf);

  // latents = x @ W_qkv  (split-K x2 -> fp32 partials)
  gemm_splitk<<<dim3(13, 16, 2), 256, 0, stream>>>(xb, 2048, wqkvT, 2048, P1, 1664, 1024);
  // fused: reduce partials + RoPE-K -> kbuf, V-transpose -> vtg, c_q -> lat
  postlat<<<dim3(32, 26), 256, 0, stream>>>(P1, lat, kbuf, vtg, cosb, sinb);

  // q = rope(c_q @ W_qdec)  -> bf16 [2048][9216]  (128^2 core, balanced 1152-block grid)
  gemm_qdec<<<dim3(72, 16), 256, 0, stream>>>(lat + 576, wqdecT, qbuf, cosb, sinb);

  // attention: 2 head-panels of 8 heads each; packed-causal E; XCD head-chunked grids
  qke_kernel<<<dim3(136, 8), 256, 0, stream>>>(qbuf, kbuf, Ebuf, lsumf, 0);
  pv_kernel<<<dim3(4, 16, 8), 256, 0, stream>>>(Ebuf, vtg, lsumf, ybuf, 0);
  qke_kernel<<<dim3(136, 8), 256, 0, stream>>>(qbuf, kbuf, Ebuf, lsumf, 8);
  pv_kernel<<<dim3(4, 16, 8), 256, 0, stream>>>(Ebuf, vtg, lsumf, ybuf, 8);

  // out = y @ W_out  (256^2 3-barrier core, split-K x4 -> fp32 partials -> fp32 out)
  gemm256_splitk<<<dim3(8, 8, 4), 512, 0, stream>>>(ybuf, 8192, woutT, 8192, Pf, 2048, 2048);
  reduce4_f32<<<4096, 256, 0, stream>>>(Pf, out, 2048 * 2048);
}